// Round 1
// baseline (192.559 us; speedup 1.0000x reference)
//
#include <hip/hip_runtime.h>

// Batched autocorrelation, X:[4096,8192] f32 -> out:[4096,64] f32.
// Strategy: per-row correlation as bf16 MFMA Gram matrices.
//   X_i[m] = x[32 i + m];  G_d[m][n] = sum_i X_i[m] * X_{i+d}[n], d=0..2
//   R_{32q+s} = sum_{m+s<32} G_q[m][m+s] + sum_{m+s>=32} G_{q+1}[m][m+s-32]
// Centering folded in algebraically (fp32):
//   C_k = R_k - mu*(2S - P_k - Q_k) + (T-k) mu^2 ;  out = C_k / C_0
// One wave per row; 3 waves/block; LDS 50.7 KB/block -> 3 blocks/CU.

typedef __bf16 bf16x8 __attribute__((ext_vector_type(8)));
typedef float f32x16 __attribute__((ext_vector_type(16)));
typedef unsigned int uint32;

#define T_LEN 8192
#define XT_STRIDE 264              // shorts per XT row; >=260 needed, mult of 8 (b128 align), 264: optimal bank spread
#define XT_SHORTS (32 * XT_STRIDE) // 8448 shorts = 16896 B per wave
#define WPB 3                      // waves (rows) per block

__device__ __forceinline__ short f2bf(float f) {
  uint32 u = __builtin_bit_cast(uint32, f);
  return (short)((u + 0x7fffu + ((u >> 16) & 1u)) >> 16); // RNE
}

__global__ __launch_bounds__(WPB * 64, 1)
void autocorr_kernel(const float* __restrict__ X, float* __restrict__ out, int nrows) {
  __shared__ short xt_all[WPB * XT_SHORTS];
  const int wave = threadIdx.x >> 6;
  const int lane = threadIdx.x & 63;
  const int row = blockIdx.x * WPB + wave;
  if (row >= nrows) return;              // no __syncthreads anywhere: waves independent
  short* xt = xt_all + wave * XT_SHORTS;

  // zero-pad XT columns 256..263 (blocks past end of row) — one b64 store per lane
  {
    int rr = lane >> 1;
    int off = 256 + ((lane & 1) << 2);
    *(int2*)(xt + rr * XT_STRIDE + off) = make_int2(0, 0);
  }

  // ---- staging: one pass over the row; fp32 sum + bf16 transpose into LDS ----
  const float4* __restrict__ Xv = (const float4*)(X + (size_t)row * T_LEN);
  float ssum = 0.f;
#pragma unroll 8
  for (int rr = 0; rr < 32; ++rr) {
    float4 v = Xv[(rr << 6) + lane];     // t = 256*rr + 4*lane + {0..3}
    ssum += (v.x + v.y) + (v.z + v.w);
    int t0 = (rr << 8) + (lane << 2);
    int b = (t0 & 31) * XT_STRIDE + (t0 >> 5);  // XT[m][i], m=t&31, i=t>>5
    xt[b]                 = f2bf(v.x);
    xt[b + XT_STRIDE]     = f2bf(v.y);
    xt[b + 2 * XT_STRIDE] = f2bf(v.z);
    xt[b + 3 * XT_STRIDE] = f2bf(v.w);
  }
  for (int d = 32; d > 0; d >>= 1) ssum += __shfl_xor(ssum, d, 64);

  // ---- G-phase: G_d (d=0,1,2) accumulated over 16 K-chunks of 16 blocks ----
  const int r = lane & 31;   // A-role: m ; B-role: n
  const int hi = lane >> 5;  // K-half
  f32x16 g0 = {}, g1 = {}, g2 = {};
  const short* xr = xt + r * XT_STRIDE + (hi << 3);
#pragma unroll 4
  for (int c = 0; c < 16; ++c) {
    const short* p = xr + (c << 4);      // elements i0+8hi+{0..9}
    int4 a4 = *(const int4*)p;           // e0..e7  (16B aligned)
    int e89 = *(const int*)(p + 8);      // e8,e9
    uint32 u0 = a4.x, u1 = a4.y, u2 = a4.z, u3 = a4.w, u4 = (uint32)e89;
    int4 b1;                             // elements 1..8 via alignbit
    b1.x = (u0 >> 16) | (u1 << 16);
    b1.y = (u1 >> 16) | (u2 << 16);
    b1.z = (u2 >> 16) | (u3 << 16);
    b1.w = (u3 >> 16) | (u4 << 16);
    int4 b2;                             // elements 2..9 = register rename
    b2.x = u1; b2.y = u2; b2.z = u3; b2.w = u4;
    bf16x8 fa = __builtin_bit_cast(bf16x8, a4);
    bf16x8 f1 = __builtin_bit_cast(bf16x8, b1);
    bf16x8 f2 = __builtin_bit_cast(bf16x8, b2);
    g0 = __builtin_amdgcn_mfma_f32_32x32x16_bf16(fa, fa, g0, 0, 0, 0); // B0 frag == A frag
    g1 = __builtin_amdgcn_mfma_f32_32x32x16_bf16(fa, f1, g1, 0, 0, 0);
    g2 = __builtin_amdgcn_mfma_f32_32x32x16_bf16(fa, f2, g2, 0, 0, 0);
  }

  // ---- dump G to LDS (reuse this wave's XT region), padded stride 33 ----
  float* gbuf = (float*)xt;
#pragma unroll
  for (int v = 0; v < 16; ++v) {
    int rm = (v & 3) + (hi << 2) + ((v >> 2) << 3); // C/D row; col = r
    gbuf[(rm)      * 33 + r] = g0[v];
    gbuf[(32 + rm) * 33 + r] = g1[v];
    gbuf[(64 + rm) * 33 + r] = g2[v];
  }

  // ---- diagonal-band sums: lane handles lag k = lane+1 ----
  int k = lane + 1;
  int s = k & 31, q = k >> 5;
  float ck = 0.f;
#pragma unroll 4
  for (int m = 0; m < 32; ++m) {
    int ms = m + s;
    int dd = q + (ms >> 5);
    ck += gbuf[(dd * 32 + m) * 33 + (ms & 31)];
  }
  float c0 = 0.f;
#pragma unroll 4
  for (int m = 0; m < 32; ++m) c0 += gbuf[m * 33 + m]; // broadcast reads

  // ---- centering correction: prefix (P_k) / suffix (Q_k) scans over lanes ----
  float P = X[(size_t)row * T_LEN + lane];
  float Q = X[(size_t)row * T_LEN + (T_LEN - 1 - lane)];
  for (int d = 1; d < 64; d <<= 1) {
    float tp = __shfl_up(P, (unsigned)d, 64);
    float tq = __shfl_up(Q, (unsigned)d, 64);
    if (lane >= d) { P += tp; Q += tq; }
  }
  float mu = ssum * (1.0f / (float)T_LEN);
  float Ck = ck - mu * (2.f * ssum - P - Q) + (float)(T_LEN - k) * mu * mu;
  float C0 = c0 - mu * 2.f * ssum + (float)T_LEN * mu * mu;
  out[(size_t)row * 64 + lane] = Ck / C0;
}

extern "C" void kernel_launch(void* const* d_in, const int* in_sizes, int n_in,
                              void* d_out, int out_size, void* d_ws, size_t ws_size,
                              hipStream_t stream) {
  const float* X = (const float*)d_in[0];
  float* out = (float*)d_out;
  int nrows = in_sizes[0] / T_LEN;  // 4096
  dim3 grid((nrows + WPB - 1) / WPB);
  autocorr_kernel<<<grid, dim3(WPB * 64), 0, stream>>>(X, out, nrows);
}

// Round 2
// 191.010 us; speedup vs baseline: 1.0081x; 1.0081x over previous
//
#include <hip/hip_runtime.h>

// Batched autocorrelation, X:[4096,8192] f32 -> out:[4096,64] f32.
// Per-row correlation as bf16 MFMA Gram matrices:
//   X_i[m] = x[32 i + m];  G_d[m][n] = sum_i X_i[m] * X_{i+d}[n], d=0..2
//   R_{32q+s} = sum_{m+s<32} G_q[m][m+s] + sum_{m+s>=32} G_{q+1}[m][m+s-32]
// Centering folded in algebraically (fp32):
//   C_k = R_k - mu*(2S - P_k - Q_k) + (T-k) mu^2 ;  out = C_k / C_0
// One wave per row; 3 waves/block; 48 KB LDS/block -> 3 blocks/CU (9 waves).
//
// R1 change: XOR-swizzled XT layout (no padding). Element (m,i) lives at
// short index m*256 + 8*((i>>3) ^ ((m>>2)&7)) + (i&7).
//  - staging ds_write_u16: 32 banks, 2 lanes/bank same-dword -> conflict-free
//  - fragment ds_read_b128: 8 XOR groups x 4 dwords -> 32 banks, 8-clk floor
// (R0 layout had 32-way write conflicts: banks = (4m)&31 with m in {0,4..28}.)

typedef __bf16 bf16x8 __attribute__((ext_vector_type(8)));
typedef float f32x16 __attribute__((ext_vector_type(16)));
typedef unsigned int uint32;

#define T_LEN 8192
#define XT_SHORTS 8192             // 32 rows x 256 shorts, block-XOR swizzled
#define WPB 3                      // waves (rows) per block

__device__ __forceinline__ short f2bf(float f) {
  uint32 u = __builtin_bit_cast(uint32, f);
  return (short)((u + 0x7fffu + ((u >> 16) & 1u)) >> 16); // RNE
}

__global__ __launch_bounds__(WPB * 64, 1)
void autocorr_kernel(const float* __restrict__ X, float* __restrict__ out, int nrows) {
  __shared__ short xt_all[WPB * XT_SHORTS];
  const int wave = threadIdx.x >> 6;
  const int lane = threadIdx.x & 63;
  const int row = blockIdx.x * WPB + wave;
  if (row >= nrows) return;              // no __syncthreads anywhere: waves independent
  short* xt = xt_all + wave * XT_SHORTS;

  // ---- staging: one pass over the row; fp32 sum + swizzled bf16 transpose ----
  const float4* __restrict__ Xv = (const float4*)(X + (size_t)row * T_LEN);
  const int gw = lane & 7;               // write-side swizzle key ((m>>2)&7 for all 4 elems)
  const int qoff = lane >> 3;            // intra-block offset (i & 7)
  const int m0 = (lane << 2) & 31;       // m of v.x; v.y/z/w are m0+1..m0+3 (no wrap)
  float ssum = 0.f;
#pragma unroll 8
  for (int rr = 0; rr < 32; ++rr) {
    float4 v = Xv[(rr << 6) + lane];     // t = 256*rr + 4*lane + {0..3}; blk = rr
    ssum += (v.x + v.y) + (v.z + v.w);
    short* wp = xt + m0 * 256 + ((rr ^ gw) << 3) + qoff;
    wp[0]   = f2bf(v.x);
    wp[256] = f2bf(v.y);
    wp[512] = f2bf(v.z);
    wp[768] = f2bf(v.w);
  }
  for (int d = 32; d > 0; d >>= 1) ssum += __shfl_xor(ssum, d, 64);

  // ---- G-phase: G_d (d=0,1,2) accumulated over 16 K-chunks of 16 blocks ----
  const int r = lane & 31;   // A-role: m ; B-role: n
  const int hi = lane >> 5;  // K-half
  const int gr = (r >> 2) & 7;           // read-side swizzle key
  const short* pr = xt + r * 256;
  f32x16 g0 = {}, g1 = {}, g2 = {};
#pragma unroll 4
  for (int c = 0; c < 16; ++c) {
    int4 a4 = *(const int4*)(pr + (((2 * c + hi) ^ gr) << 3));  // elems 0..7
    int blkE = 2 * c + hi + 1;                                   // spill block (elems 8,9)
    int e89 = *(const int*)(pr + (((blkE & 31) ^ gr) << 3));
    if (blkE == 32) e89 = 0;             // c==15, hi==1: past end of row -> zero
    uint32 u0 = a4.x, u1 = a4.y, u2 = a4.z, u3 = a4.w, u4 = (uint32)e89;
    int4 b1;                             // elements 1..8 via funnel shift
    b1.x = (u0 >> 16) | (u1 << 16);
    b1.y = (u1 >> 16) | (u2 << 16);
    b1.z = (u2 >> 16) | (u3 << 16);
    b1.w = (u3 >> 16) | (u4 << 16);
    int4 b2;                             // elements 2..9 = register rename
    b2.x = u1; b2.y = u2; b2.z = u3; b2.w = u4;
    bf16x8 fa = __builtin_bit_cast(bf16x8, a4);
    bf16x8 f1 = __builtin_bit_cast(bf16x8, b1);
    bf16x8 f2 = __builtin_bit_cast(bf16x8, b2);
    g0 = __builtin_amdgcn_mfma_f32_32x32x16_bf16(fa, fa, g0, 0, 0, 0); // B0 frag == A frag
    g1 = __builtin_amdgcn_mfma_f32_32x32x16_bf16(fa, f1, g1, 0, 0, 0);
    g2 = __builtin_amdgcn_mfma_f32_32x32x16_bf16(fa, f2, g2, 0, 0, 0);
  }

  // ---- dump G to LDS (reuse this wave's XT region), padded stride 33 ----
  float* gbuf = (float*)xt;              // 96*33*4 = 12672 B <= 16384 B
#pragma unroll
  for (int v = 0; v < 16; ++v) {
    int rm = (v & 3) + (hi << 2) + ((v >> 2) << 3); // C/D row; col = r
    gbuf[(rm)      * 33 + r] = g0[v];
    gbuf[(32 + rm) * 33 + r] = g1[v];
    gbuf[(64 + rm) * 33 + r] = g2[v];
  }

  // ---- diagonal-band sums: lane handles lag k = lane+1 ----
  int k = lane + 1;
  int s = k & 31, q = k >> 5;
  float ck = 0.f;
#pragma unroll 4
  for (int m = 0; m < 32; ++m) {
    int ms = m + s;
    int dd = q + (ms >> 5);
    ck += gbuf[(dd * 32 + m) * 33 + (ms & 31)];
  }
  float c0 = 0.f;
#pragma unroll 4
  for (int m = 0; m < 32; ++m) c0 += gbuf[m * 33 + m]; // broadcast reads

  // ---- centering correction: prefix (P_k) / suffix (Q_k) scans over lanes ----
  float P = X[(size_t)row * T_LEN + lane];
  float Q = X[(size_t)row * T_LEN + (T_LEN - 1 - lane)];
  for (int d = 1; d < 64; d <<= 1) {
    float tp = __shfl_up(P, (unsigned)d, 64);
    float tq = __shfl_up(Q, (unsigned)d, 64);
    if (lane >= d) { P += tp; Q += tq; }
  }
  float mu = ssum * (1.0f / (float)T_LEN);
  float Ck = ck - mu * (2.f * ssum - P - Q) + (float)(T_LEN - k) * mu * mu;
  float C0 = c0 - mu * 2.f * ssum + (float)T_LEN * mu * mu;
  out[(size_t)row * 64 + lane] = Ck / C0;
}

extern "C" void kernel_launch(void* const* d_in, const int* in_sizes, int n_in,
                              void* d_out, int out_size, void* d_ws, size_t ws_size,
                              hipStream_t stream) {
  const float* X = (const float*)d_in[0];
  float* out = (float*)d_out;
  int nrows = in_sizes[0] / T_LEN;  // 4096
  dim3 grid((nrows + WPB - 1) / WPB);
  autocorr_kernel<<<grid, dim3(WPB * 64), 0, stream>>>(X, out, nrows);
}

// Round 3
// 188.128 us; speedup vs baseline: 1.0236x; 1.0153x over previous
//
#include <hip/hip_runtime.h>

// Batched autocorrelation, X:[4096,8192] f32 -> out:[4096,64] f32.
// Per-row correlation as bf16 MFMA Gram matrices:
//   X_i[m] = x[32 i + m];  G_d[m][n] = sum_i X_i[m] * X_{i+d}[n], d=0..2
//   R_{32q+s} = sum_{m+s<32} G_q[m][m+s] + sum_{m+s>=32} G_{q+1}[m][m+s-32]
// Centering folded in algebraically (fp32):
//   C_k = R_k - mu*(2S - P_k - Q_k) + (T-k) mu^2 ;  out = C_k / C_0
//
// R2: NO LDS staging. A-fragment elements load straight from global:
//   e_j(lane m+32s, chunk c) = x[512c + 256s + 32j + m], j=0..9
// (per j each 32-lane half reads one contiguous 128 B line -> coalesced).
// Convert+pack to bf16 in-register; B1 via funnel shift, B2 via rename
// (identical fragment math to the R1 kernel, which passed). LDS is only a
// 6.5 KB/wave bf16 G-dump for the diagonal-band reduction.
// Occupancy: 256 thr/block, <=128 VGPR -> 4 blocks/CU = 16 waves/CU (was 9).

typedef __bf16 bf16x8 __attribute__((ext_vector_type(8)));
typedef float f32x16 __attribute__((ext_vector_type(16)));
typedef unsigned int uint32;

#define T_LEN 8192
#define WPB 4                       // waves (rows) per block
#define GB_STRIDE 34                // shorts per G row (+2 pad)
#define GB_SHORTS (96 * GB_STRIDE)  // 3 matrices x 32 rows = 6528 B / wave

__device__ __forceinline__ uint32 pack2bf(float a, float b) { // (lo=a, hi=b) RNE
  uint32 ua = __builtin_bit_cast(uint32, a);
  uint32 ub = __builtin_bit_cast(uint32, b);
  ua += 0x7fffu + ((ua >> 16) & 1u);
  ub += 0x7fffu + ((ub >> 16) & 1u);
  return (ua >> 16) | (ub & 0xffff0000u);
}
__device__ __forceinline__ short f2bf(float f) {
  uint32 u = __builtin_bit_cast(uint32, f);
  return (short)((u + 0x7fffu + ((u >> 16) & 1u)) >> 16);
}
__device__ __forceinline__ float bf2f(short h) {
  uint32 u = ((uint32)(unsigned short)h) << 16;
  return __builtin_bit_cast(float, u);
}

__global__ __launch_bounds__(WPB * 64, 4)
void autocorr_kernel(const float* __restrict__ X, float* __restrict__ out, int nrows) {
  __shared__ short gb_all[WPB * GB_SHORTS];
  const int wave = threadIdx.x >> 6;
  const int lane = threadIdx.x & 63;
  const int row = blockIdx.x * WPB + wave;
  if (row >= nrows) return;               // no barriers anywhere: waves independent
  short* gb = gb_all + wave * GB_SHORTS;

  const int m = lane & 31;                // A-role row m / B-role col n
  const int sh = lane >> 5;               // K-half s
  const float* __restrict__ base = X + (size_t)row * T_LEN + (sh << 8) + m;

  f32x16 g0 = {}, g1 = {}, g2 = {};
  float ssum = 0.f;

#define CHUNK_BODY(PP, E8, E9)                                                  \
  {                                                                             \
    float e0 = (PP)[0],   e1 = (PP)[32],  e2 = (PP)[64],  e3 = (PP)[96];        \
    float e4 = (PP)[128], e5 = (PP)[160], e6 = (PP)[192], e7 = (PP)[224];       \
    float e8 = (E8), e9 = (E9);                                                 \
    ssum += ((e0 + e1) + (e2 + e3)) + ((e4 + e5) + (e6 + e7));                  \
    uint32 u0 = pack2bf(e0, e1), u1 = pack2bf(e2, e3), u2 = pack2bf(e4, e5);    \
    uint32 u3 = pack2bf(e6, e7), u4 = pack2bf(e8, e9);                          \
    int4 a4 = make_int4((int)u0, (int)u1, (int)u2, (int)u3);                    \
    int4 b1;                                                                    \
    b1.x = (int)((u0 >> 16) | (u1 << 16));                                      \
    b1.y = (int)((u1 >> 16) | (u2 << 16));                                      \
    b1.z = (int)((u2 >> 16) | (u3 << 16));                                      \
    b1.w = (int)((u3 >> 16) | (u4 << 16));                                      \
    int4 b2 = make_int4((int)u1, (int)u2, (int)u3, (int)u4);                    \
    bf16x8 fa = __builtin_bit_cast(bf16x8, a4);                                 \
    bf16x8 f1 = __builtin_bit_cast(bf16x8, b1);                                 \
    bf16x8 f2 = __builtin_bit_cast(bf16x8, b2);                                 \
    g0 = __builtin_amdgcn_mfma_f32_32x32x16_bf16(fa, fa, g0, 0, 0, 0);          \
    g1 = __builtin_amdgcn_mfma_f32_32x32x16_bf16(fa, f1, g1, 0, 0, 0);          \
    g2 = __builtin_amdgcn_mfma_f32_32x32x16_bf16(fa, f2, g2, 0, 0, 0);          \
  }

#pragma unroll 3
  for (int c = 0; c < 15; ++c) {
    const float* p = base + (c << 9);
    CHUNK_BODY(p, p[256], p[288])
  }
  { // last chunk: spill elements for the upper half are past end of row -> 0
    const float* p = base + (15 << 9);
    float e8s = 0.f, e9s = 0.f;
    if (!sh) { e8s = p[256]; e9s = p[288]; }   // exec-masked loads, no OOB
    CHUNK_BODY(p, e8s, e9s)
  }
#undef CHUNK_BODY

  for (int d = 32; d > 0; d >>= 1) ssum += __shfl_xor(ssum, d, 64);

  // ---- dump G to LDS in bf16 (6.5 KB/wave) ----
#pragma unroll
  for (int v = 0; v < 16; ++v) {
    int rm = (v & 3) + (sh << 2) + ((v >> 2) << 3); // C/D row; col = m
    gb[(rm)      * GB_STRIDE + m] = f2bf(g0[v]);
    gb[(32 + rm) * GB_STRIDE + m] = f2bf(g1[v]);
    gb[(64 + rm) * GB_STRIDE + m] = f2bf(g2[v]);
  }

  // ---- diagonal-band sums: lane handles lag k = lane+1 ----
  int k = lane + 1;
  int s2 = k & 31, q = k >> 5;
  float ck = 0.f;
#pragma unroll 4
  for (int mm = 0; mm < 32; ++mm) {
    int ms = mm + s2;
    int dd = q + (ms >> 5);
    ck += bf2f(gb[(dd * 32 + mm) * GB_STRIDE + (ms & 31)]);
  }
  float c0 = 0.f;
#pragma unroll 4
  for (int mm = 0; mm < 32; ++mm) c0 += bf2f(gb[mm * GB_STRIDE + mm]); // broadcast

  // ---- centering correction: prefix (P_k) / suffix (Q_k) scans over lanes ----
  float P = X[(size_t)row * T_LEN + lane];
  float Q = X[(size_t)row * T_LEN + (T_LEN - 1 - lane)];
  for (int d = 1; d < 64; d <<= 1) {
    float tp = __shfl_up(P, (unsigned)d, 64);
    float tq = __shfl_up(Q, (unsigned)d, 64);
    if (lane >= d) { P += tp; Q += tq; }
  }
  float mu = ssum * (1.0f / (float)T_LEN);
  float Ck = ck - mu * (2.f * ssum - P - Q) + (float)(T_LEN - k) * mu * mu;
  float C0 = c0 - mu * 2.f * ssum + (float)T_LEN * mu * mu;
  out[(size_t)row * 64 + lane] = Ck / C0;
}

extern "C" void kernel_launch(void* const* d_in, const int* in_sizes, int n_in,
                              void* d_out, int out_size, void* d_ws, size_t ws_size,
                              hipStream_t stream) {
  const float* X = (const float*)d_in[0];
  float* out = (float*)d_out;
  int nrows = in_sizes[0] / T_LEN;  // 4096
  dim3 grid((nrows + WPB - 1) / WPB);
  autocorr_kernel<<<grid, dim3(WPB * 64), 0, stream>>>(X, out, nrows);
}